// Round 7
// baseline (574.886 us; speedup 1.0000x reference)
//
#include <hip/hip_runtime.h>

#define BDIM 256
constexpr int Bc = 2048;
constexpr int Nc = 64;
constexpr int Dc = 128;
constexpr float NEG_BIG_F = -9.0e15f;
constexpr float INV_SQRT_D = 0.08838834764831845f;  // 1/sqrt(128)

typedef __attribute__((ext_vector_type(8))) short bf16x8;
typedef __attribute__((ext_vector_type(4))) float f32x4;

#define MFMA16(A, B, C) __builtin_amdgcn_mfma_f32_16x16x32_bf16((A), (B), (C), 0, 0, 0)

__device__ __forceinline__ float bf2f(ushort u) {
    union { float f; unsigned int i; } cv;
    cv.i = ((unsigned int)u) << 16;
    return cv.f;
}
__device__ __forceinline__ ushort f2bf(float f) {
    union { float f; unsigned int i; } cv;
    cv.f = f;
    unsigned int x = cv.i;
    unsigned int r = (x >> 16) & 1u;
    x += 0x7fffu + r;                 // round-to-nearest-even
    return (ushort)(x >> 16);
}
__device__ __forceinline__ float rmax16(float v) {
#pragma unroll
    for (int off = 1; off < 16; off <<= 1) v = fmaxf(v, __shfl_xor(v, off, 64));
    return v;
}
__device__ __forceinline__ float rsum16(float v) {
#pragma unroll
    for (int off = 1; off < 16; off <<= 1) v += __shfl_xor(v, off, 64);
    return v;
}

// launch_bounds(256,2): VGPR cap 128 (round-4 win; chains, not occupancy, bind).
// NOTE: v_cvt_pk_bf16_f32 inline asm caused a 40x absmax fail (round 5) --
// conversions stay on proven f2bf bit math.
// NOTE: hbT transposed copy was perf-neutral (round 6): its writeback scatter
// conflicts offset the Phase-B read gain -- reverted.
__global__ __launch_bounds__(BDIM, 2) void star_agg_kernel(
    const float* __restrict__ hid,
    const int*   __restrict__ adj,
    const float* __restrict__ maskp,
    const float* __restrict__ a0p, const float* __restrict__ a1p,
    const float* __restrict__ a2p, const float* __restrict__ a3p,
    const float* __restrict__ q1p, const float* __restrict__ k1p,
    const float* __restrict__ q2p, const float* __restrict__ k2p,
    const float* __restrict__ wlp,
    float* __restrict__ outp)
{
    // sate in bf16 hi/lo split. Row stride 136 u16 = 272 B (16-B aligned).
    // SQ_LDS_BANK_CONFLICT ~= 7.2M is shuffle-crossbar noise (identical across
    // four tile layouts) -- do not optimize against it.
    __shared__ __align__(16) ushort hb[Nc][136];
    __shared__ __align__(16) ushort hlo[Nc][136];
    __shared__ __align__(16) ushort Pb[Nc][72];
    __shared__ __align__(16) float aL[4][Dc];
    __shared__ __align__(16) float star_s[Dc];
    __shared__ __align__(16) float kk_s[Dc], qq_s[Dc];
    __shared__ __align__(16) float vv_s[Dc], ww_s[Dc];
    __shared__ float m_s[Nc];
    __shared__ __align__(16) float beta_s[Nc];
    __shared__ float star_part[4][Dc];
    __shared__ float Ssum[4];

    const int b      = blockIdx.x;
    const int tid    = threadIdx.x;
    const int lane   = tid & 63;
    const int wv     = tid >> 6;
    const int lane15 = lane & 15;
    const int quad   = lane >> 4;

    // ---- stage: hidden -> hb/hlo (bf16 split), a -> aL, mask -> m_s
    {
        const float4* hp4 = (const float4*)(hid + (size_t)b * (Nc * Dc));
        for (int idx = tid; idx < (Nc * Dc) / 4; idx += BDIM) {
            const int r = idx >> 5;
            const int c = (idx & 31) * 4;
            const float4 v = hp4[idx];
            ushort4 hi4, lo4;
            hi4.x = f2bf(v.x); lo4.x = f2bf(v.x - bf2f(hi4.x));
            hi4.y = f2bf(v.y); lo4.y = f2bf(v.y - bf2f(hi4.y));
            hi4.z = f2bf(v.z); lo4.z = f2bf(v.z - bf2f(hi4.z));
            hi4.w = f2bf(v.w); lo4.w = f2bf(v.w - bf2f(hi4.w));
            *(ushort4*)&hb[r][c]  = hi4;
            *(ushort4*)&hlo[r][c] = lo4;
        }
        if (tid < 128) {
            const int t = tid >> 5, c4 = tid & 31;
            const float* ap = (t == 0) ? a0p : (t == 1) ? a1p : (t == 2) ? a2p : a3p;
            *(float4*)&aL[t][c4 * 4] = *(const float4*)&ap[c4 * 4];
        }
        if (tid < Nc) m_s[tid] = maskp[b * Nc + tid];
    }

    // ---- adj register cache: 16 x 4-bit per lane, loaded once during stage
    // (latency overlaps the stage conversion math; removes the cold scattered
    // adj read from the post-Phase-A select in BOTH steps)
    unsigned int apack0 = 0u, apack1 = 0u;
    {
        const int* ab = adj + (size_t)b * 4096;
#pragma unroll
        for (int n = 0; n < 4; ++n)
#pragma unroll
            for (int r = 0; r < 4; ++r) {
                const int i = wv * 16 + quad * 4 + r;
                const int j = n * 16 + lane15;
                const unsigned t = (unsigned)ab[i * 64 + j] & 15u;
                const int idx = n * 4 + r;
                if (idx < 8) apack0 |= t << (idx * 4);
                else         apack1 |= t << ((idx - 8) * 4);
            }
    }
    __syncthreads();

    // ---- star init: masked average (hi+lo precision)
    if (tid < Dc) {
        float s = 0.f, ms = 0.f;
        for (int i = 0; i < Nc; ++i) {
            const float hv = bf2f(hb[i][tid]) + bf2f(hlo[i][tid]);
            s = fmaf(hv, m_s[i], s);
            ms += m_s[i];
        }
        star_s[tid] = s / ms;
    }
    __syncthreads();

    float s2[8][4];   // sate slab (C-layout), survives into the gate

    for (int step = 0; step < 2; ++step) {
        // ---- matvec phase 1: kk = k1^T star, qq = q2^T star
        // 4 accumulators: cuts the 128-deep serial FMA chain 4x (latency-bound)
        {
            const float* Wp = (tid < Dc) ? k1p : q2p;   // wave-uniform
            const int c = tid & 127;
            float a0 = 0.f, a1 = 0.f, a2 = 0.f, a3 = 0.f;
            for (int d = 0; d < Dc; d += 4) {
                const float4 sv = *(const float4*)&star_s[d];
                a0 = fmaf(sv.x, Wp[(d + 0) * Dc + c], a0);
                a1 = fmaf(sv.y, Wp[(d + 1) * Dc + c], a1);
                a2 = fmaf(sv.z, Wp[(d + 2) * Dc + c], a2);
                a3 = fmaf(sv.w, Wp[(d + 3) * Dc + c], a3);
            }
            const float res = (a0 + a1) + (a2 + a3);
            if (tid < Dc) kk_s[c] = res; else qq_s[c] = res;
        }
        __syncthreads();
        // ---- matvec phase 2: vv = q1 kk / sqrtD, ww = k2 qq / sqrtD
        {
            const float* Wp = (tid < Dc) ? q1p : k2p;   // wave-uniform
            const float* xp = (tid < Dc) ? kk_s : qq_s;
            const int c = tid & 127;
            float a0 = 0.f, a1 = 0.f, a2 = 0.f, a3 = 0.f;
            for (int e = 0; e < Dc; e += 16) {
                const float4 w0 = *(const float4*)&Wp[c * Dc + e];
                const float4 w1 = *(const float4*)&Wp[c * Dc + e + 4];
                const float4 w2 = *(const float4*)&Wp[c * Dc + e + 8];
                const float4 w3 = *(const float4*)&Wp[c * Dc + e + 12];
                const float4 x0 = *(const float4*)&xp[e];
                const float4 x1 = *(const float4*)&xp[e + 4];
                const float4 x2 = *(const float4*)&xp[e + 8];
                const float4 x3 = *(const float4*)&xp[e + 12];
                a0 = fmaf(w0.w, x0.w, fmaf(w0.z, x0.z, fmaf(w0.y, x0.y, fmaf(w0.x, x0.x, a0))));
                a1 = fmaf(w1.w, x1.w, fmaf(w1.z, x1.z, fmaf(w1.y, x1.y, fmaf(w1.x, x1.x, a1))));
                a2 = fmaf(w2.w, x2.w, fmaf(w2.z, x2.z, fmaf(w2.y, x2.y, fmaf(w2.x, x2.x, a2))));
                a3 = fmaf(w3.w, x3.w, fmaf(w3.z, x3.z, fmaf(w3.y, x3.y, fmaf(w3.x, x3.x, a3))));
            }
            const float res = ((a0 + a1) + (a2 + a3)) * INV_SQRT_D;
            if (tid < Dc) vv_s[c] = res; else ww_s[c] = res;
        }
        __syncthreads();

        // ---- Phase A: relation logits via split-bf16 MFMA.
        f32x4 eacc[4][4];   // [t][ntile]
#pragma unroll
        for (int t = 0; t < 4; ++t)
#pragma unroll
            for (int n = 0; n < 4; ++n) eacc[t][n] = (f32x4)0.f;

        const int arow = wv * 16 + lane15;
#pragma unroll
        for (int kc = 0; kc < 4; ++kc) {
            const int ko = kc * 32 + quad * 8;
            const bf16x8 hh = *(const bf16x8*)&hb[arow][ko];
            const bf16x8 hl = *(const bf16x8*)&hlo[arow][ko];
            float hx[8];
#pragma unroll
            for (int e = 0; e < 8; ++e)
                hx[e] = bf2f((ushort)hh[e]) + bf2f((ushort)hl[e]);
            bf16x8 Ahi[4], Alo[4];
#pragma unroll
            for (int t = 0; t < 4; ++t) {
                const float4 a0 = *(const float4*)&aL[t][ko];
                const float4 a1 = *(const float4*)&aL[t][ko + 4];
                const float av[8] = {a0.x, a0.y, a0.z, a0.w, a1.x, a1.y, a1.z, a1.w};
#pragma unroll
                for (int e = 0; e < 8; ++e) {
                    const float p = hx[e] * av[e];
                    const ushort ph = f2bf(p);
                    const ushort pl = f2bf(p - bf2f(ph));
                    Ahi[t][e] = (short)ph;
                    Alo[t][e] = (short)pl;
                }
            }
#pragma unroll
            for (int n = 0; n < 4; ++n) {
                const int brow = n * 16 + lane15;
                const bf16x8 Bh = *(const bf16x8*)&hb[brow][ko];
                const bf16x8 Bl = *(const bf16x8*)&hlo[brow][ko];
#pragma unroll
                for (int t = 0; t < 4; ++t) {
                    eacc[t][n] = MFMA16(Ahi[t], Bh, eacc[t][n]);
                    eacc[t][n] = MFMA16(Ahi[t], Bl, eacc[t][n]);
                    eacc[t][n] = MFMA16(Alo[t], Bh, eacc[t][n]);
                }
            }
        }

        // ---- selection by adj (register-cached) + leaky
        float lg[4][4];   // [ntile][reg]
#pragma unroll
        for (int n = 0; n < 4; ++n) {
#pragma unroll
            for (int r = 0; r < 4; ++r) {
                const int idx = n * 4 + r;
                const int t = (int)((idx < 8 ? (apack0 >> (idx * 4))
                                             : (apack1 >> ((idx - 8) * 4))) & 15u);
                const float v0 = eacc[0][n][r], v1 = eacc[1][n][r];
                const float v2 = eacc[2][n][r], v3 = eacc[3][n][r];
                const float sel = (t == 1) ? v0 : (t == 2) ? v1 : (t == 3) ? v2 : v3;
                const float e = (t >= 1 && t <= 4) ? ((sel >= 0.f) ? sel : 0.2f * sel)
                                                   : NEG_BIG_F;
                lg[n][r] = e;
            }
        }

        // ---- in-register softmax over j (16 lanes x 4 ntiles) -> P (bf16 LDS)
#pragma unroll
        for (int r = 0; r < 4; ++r) {
            float mx = fmaxf(fmaxf(lg[0][r], lg[1][r]), fmaxf(lg[2][r], lg[3][r]));
            mx = rmax16(mx);
            float pr[4], s = 0.f;
#pragma unroll
            for (int n = 0; n < 4; ++n) { pr[n] = __expf(lg[n][r] - mx); s += pr[n]; }
            s = rsum16(s);
            const float inv = 1.f / s;
            const int irow = wv * 16 + quad * 4 + r;
#pragma unroll
            for (int n = 0; n < 4; ++n)
                Pb[irow][n * 16 + lane15] = f2bf(pr[n] * inv);
        }
        // no barrier: Phase B reads back only this wave's OWN 16 Pb rows;
        // same-wave LDS write->read is ordered by lgkmcnt.

        // ---- Phase B: sate1 = P @ sate
        f32x4 s1[8];
#pragma unroll
        for (int nd = 0; nd < 8; ++nd) s1[nd] = (f32x4)0.f;
#pragma unroll
        for (int kc2 = 0; kc2 < 2; ++kc2) {
            const int ko = kc2 * 32 + quad * 8;
            const bf16x8 Pa = *(const bf16x8*)&Pb[wv * 16 + lane15][ko];
#pragma unroll
            for (int nd = 0; nd < 8; ++nd) {
                const int dc = nd * 16 + lane15;
                bf16x8 Bf;
#pragma unroll
                for (int jj = 0; jj < 8; ++jj) Bf[jj] = (short)hb[ko + jj][dc];
                s1[nd] = MFMA16(Pa, Bf, s1[nd]);
            }
        }

        // ---- alpha blend: sate2 = (1-alpha)*sate1 + alpha*star
        float vvv[8], stv[8];
#pragma unroll
        for (int nt = 0; nt < 8; ++nt) {
            vvv[nt] = vv_s[nt * 16 + lane15];
            stv[nt] = star_s[nt * 16 + lane15];
        }
#pragma unroll
        for (int r = 0; r < 4; ++r) {
            float part = 0.f;
#pragma unroll
            for (int nt = 0; nt < 8; ++nt) part = fmaf(s1[nt][r], vvv[nt], part);
            const float al = rsum16(part);
#pragma unroll
            for (int nt = 0; nt < 8; ++nt)
                s2[nt][r] = (1.f - al) * s1[nt][r] + al * stv[nt];
        }

        // ---- beta logits (masked, finite sentinel)
        float www[8];
#pragma unroll
        for (int nt = 0; nt < 8; ++nt) www[nt] = ww_s[nt * 16 + lane15];
        float bm[4];
#pragma unroll
        for (int r = 0; r < 4; ++r) {
            float part = 0.f;
#pragma unroll
            for (int nt = 0; nt < 8; ++nt) part = fmaf(s2[nt][r], www[nt], part);
            const float bj = rsum16(part);
            const int j = wv * 16 + quad * 4 + r;
            bm[r] = (m_s[j] == 0.f) ? NEG_BIG_F : bj;
            if (lane15 == 0) beta_s[j] = bm[r];
        }
        __syncthreads();

        // ---- star = softmax(beta) @ sate2 : per-wave partials + sate2 -> LDS
        {
            float mx = NEG_BIG_F;
#pragma unroll
            for (int j4 = 0; j4 < 16; ++j4) {
                const float4 bv = *(const float4*)&beta_s[j4 * 4];
                mx = fmaxf(mx, fmaxf(fmaxf(bv.x, bv.y), fmaxf(bv.z, bv.w)));
            }
            float p[4];
#pragma unroll
            for (int r = 0; r < 4; ++r) p[r] = __expf(bm[r] - mx);
            float part[8];
#pragma unroll
            for (int nt = 0; nt < 8; ++nt) {
                float v = 0.f;
#pragma unroll
                for (int r = 0; r < 4; ++r) v = fmaf(p[r], s2[nt][r], v);
                v += __shfl_xor(v, 16, 64);
                v += __shfl_xor(v, 32, 64);
                part[nt] = v;
            }
            if (lane < 16) {
#pragma unroll
                for (int nt = 0; nt < 8; ++nt)
                    star_part[wv][nt * 16 + lane15] = part[nt];
            }
            // per-wave softmax denominator partial (saves 64-exp recompute)
            float pw = p[0] + p[1] + p[2] + p[3];
            pw += __shfl_xor(pw, 16, 64);
            pw += __shfl_xor(pw, 32, 64);
            if (lane == 0) Ssum[wv] = pw;

            // sate2 -> hb/hlo (for next step's MFMA operands / gate)
#pragma unroll
            for (int nt = 0; nt < 8; ++nt) {
#pragma unroll
                for (int r = 0; r < 4; ++r) {
                    const float v = s2[nt][r];
                    const ushort hi = f2bf(v);
                    const ushort lo = f2bf(v - bf2f(hi));
                    const int row = wv * 16 + quad * 4 + r;
                    const int c   = nt * 16 + lane15;
                    hb[row][c]  = hi;
                    hlo[row][c] = lo;
                }
            }
        }
        __syncthreads();
        if (tid < Dc) {
            const float S = Ssum[0] + Ssum[1] + Ssum[2] + Ssum[3];
            const float tot = star_part[0][tid] + star_part[1][tid]
                            + star_part[2][tid] + star_part[3][tid];
            star_s[tid] = tot / S;
        }
        __syncthreads();
    }

    // ---- gate GEMM: logits = [hidden, sate2] @ W^T via MFMA
    f32x4 g[8];
#pragma unroll
    for (int n = 0; n < 8; ++n) g[n] = (f32x4)0.f;
    const int arow_g = wv * 16 + lane15;
    const float* hrowA = hid + ((size_t)b * 64 + arow_g) * Dc;
#pragma unroll
    for (int kc = 0; kc < 8; ++kc) {
        bf16x8 Ah, Al;
        const bool has_lo = (kc >= 4);
        if (!has_lo) {
            const int co = kc * 32 + quad * 8;
            const float4 h0 = *(const float4*)&hrowA[co];
            const float4 h1 = *(const float4*)&hrowA[co + 4];
            const float hv[8] = {h0.x, h0.y, h0.z, h0.w, h1.x, h1.y, h1.z, h1.w};
#pragma unroll
            for (int e = 0; e < 8; ++e) Ah[e] = (short)f2bf(hv[e]);
        } else {
            const int co = (kc - 4) * 32 + quad * 8;
            Ah = *(const bf16x8*)&hb[arow_g][co];
            Al = *(const bf16x8*)&hlo[arow_g][co];
        }
#pragma unroll
        for (int n = 0; n < 8; ++n) {
            const int orow = n * 16 + lane15;
            const float* wr = wlp + orow * 256 + kc * 32 + quad * 8;
            const float4 w0 = *(const float4*)&wr[0];
            const float4 w1 = *(const float4*)&wr[4];
            const float wvv[8] = {w0.x, w0.y, w0.z, w0.w, w1.x, w1.y, w1.z, w1.w};
            bf16x8 Bf;
#pragma unroll
            for (int e = 0; e < 8; ++e) Bf[e] = (short)f2bf(wvv[e]);
            g[n] = MFMA16(Ah, Bf, g[n]);
            if (has_lo) g[n] = MFMA16(Al, Bf, g[n]);
        }
    }

    // ---- epilogue: out = g*hidden + (1-g)*sate2 ; star output
#pragma unroll
    for (int n = 0; n < 8; ++n) {
#pragma unroll
        for (int r = 0; r < 4; ++r) {
            const int i = wv * 16 + quad * 4 + r;
            const int o = n * 16 + lane15;
            const float gg = 1.f / (1.f + __expf(-g[n][r]));
            const float hv = hid[((size_t)b * 64 + i) * Dc + o];
            outp[((size_t)b * 64 + i) * Dc + o] = gg * hv + (1.f - gg) * s2[n][r];
        }
    }
    if (tid < Dc)
        outp[(size_t)Bc * Nc * Dc + (size_t)b * Dc + tid] = star_s[tid];
}

extern "C" void kernel_launch(void* const* d_in, const int* in_sizes, int n_in,
                              void* d_out, int out_size, void* d_ws, size_t ws_size,
                              hipStream_t stream) {
    const float* hid  = (const float*)d_in[0];
    const int*   adj  = (const int*)d_in[1];
    const float* mask = (const float*)d_in[2];
    const float* a0   = (const float*)d_in[3];
    const float* a1   = (const float*)d_in[4];
    const float* a2   = (const float*)d_in[5];
    const float* a3   = (const float*)d_in[6];
    const float* q1   = (const float*)d_in[7];
    const float* k1   = (const float*)d_in[8];
    const float* q2   = (const float*)d_in[9];
    const float* k2   = (const float*)d_in[10];
    const float* wl   = (const float*)d_in[11];
    float* out = (float*)d_out;

    star_agg_kernel<<<Bc, BDIM, 0, stream>>>(hid, adj, mask, a0, a1, a2, a3,
                                             q1, k1, q2, k2, wl, out);
}

// Round 8
// 437.823 us; speedup vs baseline: 1.3131x; 1.3131x over previous
//
#include <hip/hip_runtime.h>

#define BDIM 256
constexpr int Bc = 2048;
constexpr int Nc = 64;
constexpr int Dc = 128;
constexpr float NEG_BIG_F = -9.0e15f;
constexpr float INV_SQRT_D = 0.08838834764831845f;  // 1/sqrt(128)

typedef __attribute__((ext_vector_type(8))) short bf16x8;
typedef __attribute__((ext_vector_type(4))) float f32x4;

#define MFMA16(A, B, C) __builtin_amdgcn_mfma_f32_16x16x32_bf16((A), (B), (C), 0, 0, 0)

__device__ __forceinline__ float bf2f(ushort u) {
    union { float f; unsigned int i; } cv;
    cv.i = ((unsigned int)u) << 16;
    return cv.f;
}
__device__ __forceinline__ ushort f2bf(float f) {
    union { float f; unsigned int i; } cv;
    cv.f = f;
    unsigned int x = cv.i;
    unsigned int r = (x >> 16) & 1u;
    x += 0x7fffu + r;                 // round-to-nearest-even
    return (ushort)(x >> 16);
}
__device__ __forceinline__ float rmax16(float v) {
#pragma unroll
    for (int off = 1; off < 16; off <<= 1) v = fmaxf(v, __shfl_xor(v, off, 64));
    return v;
}
__device__ __forceinline__ float rsum16(float v) {
#pragma unroll
    for (int off = 1; off < 16; off <<= 1) v += __shfl_xor(v, off, 64);
    return v;
}

// launch_bounds(256,2): VGPR cap 256-tier; compiler lands ~120 spill-free.
// SPILL DETECTOR: WRITE_SIZE must stay ~66.5 MB (= output demand). Rounds
// 0/3/7 showed 185-290 MB = scratch spill round-trips (~320 B/thread, r7).
// Keep register pressure at round-4 levels: no big float4 temp blocks, no
// long-lived caches across Phase A (eacc uses 64 VGPRs at peak there).
// NOTE: v_cvt_pk_bf16_f32 inline asm = 40x absmax fail (r5). f2bf only.
// NOTE: hbT transposed copy perf-neutral (r6): writeback scatter conflicts
// offset the Phase-B read gain. SQ_LDS_BANK_CONFLICT ~7.2M is shuffle noise.
__global__ __launch_bounds__(BDIM, 2) void star_agg_kernel(
    const float* __restrict__ hid,
    const int*   __restrict__ adj,
    const float* __restrict__ maskp,
    const float* __restrict__ a0p, const float* __restrict__ a1p,
    const float* __restrict__ a2p, const float* __restrict__ a3p,
    const float* __restrict__ q1p, const float* __restrict__ k1p,
    const float* __restrict__ q2p, const float* __restrict__ k2p,
    const float* __restrict__ wlp,
    float* __restrict__ outp)
{
    __shared__ __align__(16) ushort hb[Nc][136];
    __shared__ __align__(16) ushort hlo[Nc][136];
    __shared__ __align__(16) ushort Pb[Nc][72];
    __shared__ float aL[4][Dc];
    __shared__ float star_s[Dc];
    __shared__ float kk_s[Dc], qq_s[Dc];
    __shared__ float vv_s[Dc], ww_s[Dc];
    __shared__ float m_s[Nc];
    __shared__ float beta_s[Nc];
    __shared__ float star_part[4][Dc];
    __shared__ float Ssum[4];

    const int b      = blockIdx.x;
    const int tid    = threadIdx.x;
    const int lane   = tid & 63;
    const int wv     = tid >> 6;
    const int lane15 = lane & 15;
    const int quad   = lane >> 4;

    // ---- stage: hidden -> hb/hlo (bf16 split), a -> aL, mask -> m_s
    {
        const float4* hp4 = (const float4*)(hid + (size_t)b * (Nc * Dc));
        for (int idx = tid; idx < (Nc * Dc) / 4; idx += BDIM) {
            const int r = idx >> 5;
            const int c = (idx & 31) * 4;
            const float4 v = hp4[idx];
            ushort4 hi4, lo4;
            hi4.x = f2bf(v.x); lo4.x = f2bf(v.x - bf2f(hi4.x));
            hi4.y = f2bf(v.y); lo4.y = f2bf(v.y - bf2f(hi4.y));
            hi4.z = f2bf(v.z); lo4.z = f2bf(v.z - bf2f(hi4.z));
            hi4.w = f2bf(v.w); lo4.w = f2bf(v.w - bf2f(hi4.w));
            *(ushort4*)&hb[r][c]  = hi4;
            *(ushort4*)&hlo[r][c] = lo4;
        }
        if (tid < 128) {
            const int t = tid >> 5, c4 = tid & 31;
            const float* ap = (t == 0) ? a0p : (t == 1) ? a1p : (t == 2) ? a2p : a3p;
            *(float4*)&aL[t][c4 * 4] = *(const float4*)&ap[c4 * 4];
        }
        if (tid < Nc) m_s[tid] = maskp[b * Nc + tid];
    }
    __syncthreads();

    // ---- star init: masked average
    if (tid < Dc) {
        float s = 0.f, ms = 0.f;
        for (int i = 0; i < Nc; ++i) {
            const float hv = bf2f(hb[i][tid]) + bf2f(hlo[i][tid]);
            s = fmaf(hv, m_s[i], s);
            ms += m_s[i];
        }
        star_s[tid] = s / ms;
    }
    __syncthreads();

    float s2[8][4];   // sate slab (C-layout), survives into the gate

    for (int step = 0; step < 2; ++step) {
        // ---- matvec phase 1: kk = k1^T star, qq = q2^T star.
        // NO barrier after: results consumed by mv2 only AFTER the barrier
        // that follows softmax. Its load latency overlaps Phase A's MFMA work
        // (wave drift + in-flight vmcnt instead of a dedicated fence).
        if (tid < Dc) {
            const int c = tid;
            float s = 0.f;
            for (int d = 0; d < Dc; ++d) s = fmaf(star_s[d], k1p[d * Dc + c], s);
            kk_s[c] = s;
        } else {
            const int c = tid - Dc;
            float s = 0.f;
            for (int d = 0; d < Dc; ++d) s = fmaf(star_s[d], q2p[d * Dc + c], s);
            qq_s[c] = s;
        }

        // ---- Phase A: relation logits via split-bf16 MFMA.
        f32x4 eacc[4][4];   // [t][ntile]
#pragma unroll
        for (int t = 0; t < 4; ++t)
#pragma unroll
            for (int n = 0; n < 4; ++n) eacc[t][n] = (f32x4)0.f;

        const int arow = wv * 16 + lane15;
#pragma unroll
        for (int kc = 0; kc < 4; ++kc) {
            const int ko = kc * 32 + quad * 8;
            const bf16x8 hh = *(const bf16x8*)&hb[arow][ko];
            const bf16x8 hl = *(const bf16x8*)&hlo[arow][ko];
            float hx[8];
#pragma unroll
            for (int e = 0; e < 8; ++e)
                hx[e] = bf2f((ushort)hh[e]) + bf2f((ushort)hl[e]);
            bf16x8 Ahi[4], Alo[4];
#pragma unroll
            for (int t = 0; t < 4; ++t) {
                const float4 a0 = *(const float4*)&aL[t][ko];
                const float4 a1 = *(const float4*)&aL[t][ko + 4];
                const float av[8] = {a0.x, a0.y, a0.z, a0.w, a1.x, a1.y, a1.z, a1.w};
#pragma unroll
                for (int e = 0; e < 8; ++e) {
                    const float p = hx[e] * av[e];
                    const ushort ph = f2bf(p);
                    const ushort pl = f2bf(p - bf2f(ph));
                    Ahi[t][e] = (short)ph;
                    Alo[t][e] = (short)pl;
                }
            }
#pragma unroll
            for (int n = 0; n < 4; ++n) {
                const int brow = n * 16 + lane15;
                const bf16x8 Bh = *(const bf16x8*)&hb[brow][ko];
                const bf16x8 Bl = *(const bf16x8*)&hlo[brow][ko];
#pragma unroll
                for (int t = 0; t < 4; ++t) {
                    eacc[t][n] = MFMA16(Ahi[t], Bh, eacc[t][n]);
                    eacc[t][n] = MFMA16(Ahi[t], Bl, eacc[t][n]);
                    eacc[t][n] = MFMA16(Alo[t], Bh, eacc[t][n]);
                }
            }
        }

        // ---- selection by adj + leaky (adj inline; register-cache risks
        // pressure -- r7 lesson)
        float lg[4][4];   // [ntile][reg]
#pragma unroll
        for (int n = 0; n < 4; ++n) {
#pragma unroll
            for (int r = 0; r < 4; ++r) {
                const int i = wv * 16 + quad * 4 + r;
                const int j = n * 16 + lane15;
                const int t = adj[(size_t)b * 4096 + i * 64 + j];
                const float v0 = eacc[0][n][r], v1 = eacc[1][n][r];
                const float v2 = eacc[2][n][r], v3 = eacc[3][n][r];
                const float sel = (t == 1) ? v0 : (t == 2) ? v1 : (t == 3) ? v2 : v3;
                const float e = (t >= 1 && t <= 4) ? ((sel >= 0.f) ? sel : 0.2f * sel)
                                                   : NEG_BIG_F;
                lg[n][r] = e;
            }
        }

        // ---- in-register softmax over j -> P (bf16 LDS)
#pragma unroll
        for (int r = 0; r < 4; ++r) {
            float mx = fmaxf(fmaxf(lg[0][r], lg[1][r]), fmaxf(lg[2][r], lg[3][r]));
            mx = rmax16(mx);
            float pr[4], s = 0.f;
#pragma unroll
            for (int n = 0; n < 4; ++n) { pr[n] = __expf(lg[n][r] - mx); s += pr[n]; }
            s = rsum16(s);
            const float inv = 1.f / s;
            const int irow = wv * 16 + quad * 4 + r;
#pragma unroll
            for (int n = 0; n < 4; ++n)
                Pb[irow][n * 16 + lane15] = f2bf(pr[n] * inv);
        }
        __syncthreads();   // BAR_a: kk/qq ready for mv2 (and Pb globally visible)

        // ---- matvec phase 2: vv = q1 kk / sqrtD, ww = k2 qq / sqrtD.
        // NO barrier after: results consumed after BAR_b; load latency
        // overlaps Phase B's LDS reads + MFMAs.
        if (tid < Dc) {
            const int c = tid;
            float s = 0.f;
            for (int e4 = 0; e4 < Dc; e4 += 4) {
                const float4 qv = *(const float4*)&q1p[c * Dc + e4];
                s = fmaf(qv.w, kk_s[e4 + 3], fmaf(qv.z, kk_s[e4 + 2],
                    fmaf(qv.y, kk_s[e4 + 1], fmaf(qv.x, kk_s[e4], s))));
            }
            vv_s[c] = s * INV_SQRT_D;
        } else {
            const int c = tid - Dc;
            float s = 0.f;
            for (int e4 = 0; e4 < Dc; e4 += 4) {
                const float4 kv = *(const float4*)&k2p[c * Dc + e4];
                s = fmaf(kv.w, qq_s[e4 + 3], fmaf(kv.z, qq_s[e4 + 2],
                    fmaf(kv.y, qq_s[e4 + 1], fmaf(kv.x, qq_s[e4], s))));
            }
            ww_s[c] = s * INV_SQRT_D;
        }

        // ---- Phase B: sate1 = P @ sate
        f32x4 s1[8];
#pragma unroll
        for (int nd = 0; nd < 8; ++nd) s1[nd] = (f32x4)0.f;
#pragma unroll
        for (int kc2 = 0; kc2 < 2; ++kc2) {
            const int ko = kc2 * 32 + quad * 8;
            const bf16x8 Pa = *(const bf16x8*)&Pb[wv * 16 + lane15][ko];
#pragma unroll
            for (int nd = 0; nd < 8; ++nd) {
                const int dc = nd * 16 + lane15;
                bf16x8 Bf;
#pragma unroll
                for (int jj = 0; jj < 8; ++jj) Bf[jj] = (short)hb[ko + jj][dc];
                s1[nd] = MFMA16(Pa, Bf, s1[nd]);
            }
        }
        __syncthreads();   // BAR_b: vv/ww ready (cross-wave reads below)

        // ---- alpha blend: sate2 = (1-alpha)*sate1 + alpha*star
        float vvv[8], stv[8];
#pragma unroll
        for (int nt = 0; nt < 8; ++nt) {
            vvv[nt] = vv_s[nt * 16 + lane15];
            stv[nt] = star_s[nt * 16 + lane15];
        }
#pragma unroll
        for (int r = 0; r < 4; ++r) {
            float part = 0.f;
#pragma unroll
            for (int nt = 0; nt < 8; ++nt) part = fmaf(s1[nt][r], vvv[nt], part);
            const float al = rsum16(part);
#pragma unroll
            for (int nt = 0; nt < 8; ++nt)
                s2[nt][r] = (1.f - al) * s1[nt][r] + al * stv[nt];
        }

        // ---- beta logits (masked, finite sentinel)
        float www[8];
#pragma unroll
        for (int nt = 0; nt < 8; ++nt) www[nt] = ww_s[nt * 16 + lane15];
        float bm[4];
#pragma unroll
        for (int r = 0; r < 4; ++r) {
            float part = 0.f;
#pragma unroll
            for (int nt = 0; nt < 8; ++nt) part = fmaf(s2[nt][r], www[nt], part);
            const float bj = rsum16(part);
            const int j = wv * 16 + quad * 4 + r;
            bm[r] = (m_s[j] == 0.f) ? NEG_BIG_F : bj;
            if (lane15 == 0) beta_s[j] = bm[r];
        }
        __syncthreads();   // BAR_c: beta_s ready

        // ---- star = softmax(beta) @ sate2 : per-wave partials + sate2 -> LDS
        {
            float mx = NEG_BIG_F;
#pragma unroll
            for (int j4 = 0; j4 < 16; ++j4) {
                const float4 bv = *(const float4*)&beta_s[j4 * 4];
                mx = fmaxf(mx, fmaxf(fmaxf(bv.x, bv.y), fmaxf(bv.z, bv.w)));
            }
            float p[4];
#pragma unroll
            for (int r = 0; r < 4; ++r) p[r] = __expf(bm[r] - mx);
            float part[8];
#pragma unroll
            for (int nt = 0; nt < 8; ++nt) {
                float v = 0.f;
#pragma unroll
                for (int r = 0; r < 4; ++r) v = fmaf(p[r], s2[nt][r], v);
                v += __shfl_xor(v, 16, 64);
                v += __shfl_xor(v, 32, 64);
                part[nt] = v;
            }
            if (lane < 16) {
#pragma unroll
                for (int nt = 0; nt < 8; ++nt)
                    star_part[wv][nt * 16 + lane15] = part[nt];
            }
            // per-wave softmax denominator partial (saves 64-exp recompute)
            float pw = p[0] + p[1] + p[2] + p[3];
            pw += __shfl_xor(pw, 16, 64);
            pw += __shfl_xor(pw, 32, 64);
            if (lane == 0) Ssum[wv] = pw;

            // sate2 -> hb/hlo (for next step's MFMA operands / gate)
#pragma unroll
            for (int nt = 0; nt < 8; ++nt) {
#pragma unroll
                for (int r = 0; r < 4; ++r) {
                    const float v = s2[nt][r];
                    const ushort hi = f2bf(v);
                    const ushort lo = f2bf(v - bf2f(hi));
                    const int row = wv * 16 + quad * 4 + r;
                    const int c   = nt * 16 + lane15;
                    hb[row][c]  = hi;
                    hlo[row][c] = lo;
                }
            }
        }
        __syncthreads();   // BAR_d: star_part/Ssum ready
        if (tid < Dc) {
            const float S = Ssum[0] + Ssum[1] + Ssum[2] + Ssum[3];
            const float tot = star_part[0][tid] + star_part[1][tid]
                            + star_part[2][tid] + star_part[3][tid];
            star_s[tid] = tot / S;
        }
        __syncthreads();   // BAR_e: star_s ready for next step / nothing after
    }

    // ---- gate GEMM: logits = [hidden, sate2] @ W^T via MFMA
    f32x4 g[8];
#pragma unroll
    for (int n = 0; n < 8; ++n) g[n] = (f32x4)0.f;
    const int arow_g = wv * 16 + lane15;
    const float* hrowA = hid + ((size_t)b * 64 + arow_g) * Dc;
#pragma unroll
    for (int kc = 0; kc < 8; ++kc) {
        bf16x8 Ah, Al;
        const bool has_lo = (kc >= 4);
        if (!has_lo) {
            const int co = kc * 32 + quad * 8;
            const float4 h0 = *(const float4*)&hrowA[co];
            const float4 h1 = *(const float4*)&hrowA[co + 4];
            const float hv[8] = {h0.x, h0.y, h0.z, h0.w, h1.x, h1.y, h1.z, h1.w};
#pragma unroll
            for (int e = 0; e < 8; ++e) Ah[e] = (short)f2bf(hv[e]);
        } else {
            const int co = (kc - 4) * 32 + quad * 8;
            Ah = *(const bf16x8*)&hb[arow_g][co];
            Al = *(const bf16x8*)&hlo[arow_g][co];
        }
#pragma unroll
        for (int n = 0; n < 8; ++n) {
            const int orow = n * 16 + lane15;
            const float* wr = wlp + orow * 256 + kc * 32 + quad * 8;
            const float4 w0 = *(const float4*)&wr[0];
            const float4 w1 = *(const float4*)&wr[4];
            const float wvv[8] = {w0.x, w0.y, w0.z, w0.w, w1.x, w1.y, w1.z, w1.w};
            bf16x8 Bf;
#pragma unroll
            for (int e = 0; e < 8; ++e) Bf[e] = (short)f2bf(wvv[e]);
            g[n] = MFMA16(Ah, Bf, g[n]);
            if (has_lo) g[n] = MFMA16(Al, Bf, g[n]);
        }
    }

    // ---- epilogue: out = g*hidden + (1-g)*sate2 ; star output
#pragma unroll
    for (int n = 0; n < 8; ++n) {
#pragma unroll
        for (int r = 0; r < 4; ++r) {
            const int i = wv * 16 + quad * 4 + r;
            const int o = n * 16 + lane15;
            const float gg = 1.f / (1.f + __expf(-g[n][r]));
            const float hv = hid[((size_t)b * 64 + i) * Dc + o];
            outp[((size_t)b * 64 + i) * Dc + o] = gg * hv + (1.f - gg) * s2[n][r];
        }
    }
    if (tid < Dc)
        outp[(size_t)Bc * Nc * Dc + (size_t)b * Dc + tid] = star_s[tid];
}

extern "C" void kernel_launch(void* const* d_in, const int* in_sizes, int n_in,
                              void* d_out, int out_size, void* d_ws, size_t ws_size,
                              hipStream_t stream) {
    const float* hid  = (const float*)d_in[0];
    const int*   adj  = (const int*)d_in[1];
    const float* mask = (const float*)d_in[2];
    const float* a0   = (const float*)d_in[3];
    const float* a1   = (const float*)d_in[4];
    const float* a2   = (const float*)d_in[5];
    const float* a3   = (const float*)d_in[6];
    const float* q1   = (const float*)d_in[7];
    const float* k1   = (const float*)d_in[8];
    const float* q2   = (const float*)d_in[9];
    const float* k2   = (const float*)d_in[10];
    const float* wl   = (const float*)d_in[11];
    float* out = (float*)d_out;

    star_agg_kernel<<<Bc, BDIM, 0, stream>>>(hid, adj, mask, a0, a1, a2, a3,
                                             q1, k1, q2, k2, wl, out);
}

// Round 9
// 432.686 us; speedup vs baseline: 1.3286x; 1.0119x over previous
//
#include <hip/hip_runtime.h>

#define BDIM 256
constexpr int Bc = 2048;
constexpr int Nc = 64;
constexpr int Dc = 128;
constexpr float NEG_BIG_F = -9.0e15f;
constexpr float INV_SQRT_D = 0.08838834764831845f;  // 1/sqrt(128)

typedef __attribute__((ext_vector_type(8))) short bf16x8;
typedef __attribute__((ext_vector_type(4))) float f32x4;

#define MFMA16(A, B, C) __builtin_amdgcn_mfma_f32_16x16x32_bf16((A), (B), (C), 0, 0, 0)

__device__ __forceinline__ float bf2f(ushort u) {
    union { float f; unsigned int i; } cv;
    cv.i = ((unsigned int)u) << 16;
    return cv.f;
}
__device__ __forceinline__ ushort f2bf(float f) {
    union { float f; unsigned int i; } cv;
    cv.f = f;
    unsigned int x = cv.i;
    unsigned int r = (x >> 16) & 1u;
    x += 0x7fffu + r;                 // round-to-nearest-even
    return (ushort)(x >> 16);
}
// pack {trunc_bf16(a), trunc_bf16(b)} -> one u32 in ONE VALU op (v_perm_b32).
// Byte sel 0x07060302: dst.b0=a.b2 dst.b1=a.b3 (lo16=trunc a),
//                      dst.b2=b.b2 dst.b3=b.b3 (hi16=trunc b).
// Compiler-visible builtin (NOT inline asm -- m240: hand-asm cvt_pk defeats
// scheduling; r5: cvt_pk asm broke correctness).
__device__ __forceinline__ unsigned int pkt(float a, float b) {
    union { float f; unsigned int u; } x, y; x.f = a; y.f = b;
    return __builtin_amdgcn_perm(y.u, x.u, 0x07060302u);
}
__device__ __forceinline__ float u2f_lo(unsigned int u) {   // float from low16
    union { float f; unsigned int i; } cv; cv.i = u << 16; return cv.f;
}
__device__ __forceinline__ float u2f_hi(unsigned int u) {   // float from high16
    union { float f; unsigned int i; } cv; cv.i = u & 0xffff0000u; return cv.f;
}
__device__ __forceinline__ float rmax16(float v) {
#pragma unroll
    for (int off = 1; off < 16; off <<= 1) v = fmaxf(v, __shfl_xor(v, off, 64));
    return v;
}
__device__ __forceinline__ float rsum16(float v) {
#pragma unroll
    for (int off = 1; off < 16; off <<= 1) v += __shfl_xor(v, off, 64);
    return v;
}

// launch_bounds(256,2): VGPR cap 256-tier; lands ~120 spill-free.
// SPILL DETECTOR (r7 lesson): WRITE_SIZE must stay ~66.5 MB (= output
// demand); 185-290 MB = scratch spill round-trips. Keep register pressure
// at round-4 levels.
// Truncation policy: pkt (1-op v_perm trunc-pack) ONLY where (a) the hi/lo
// split self-compensates (Phase A repack: Alo = p - trunc(p) exactly), or
// (b) low-sensitivity (gate W / gate hidden-A -> sigmoid). Stage split,
// sate2 writeback, Pb keep RNE f2bf (hb-hi is consumed standalone by
// Phase B; protects absmax).
__global__ __launch_bounds__(BDIM, 2) void star_agg_kernel(
    const float* __restrict__ hid,
    const int*   __restrict__ adj,
    const float* __restrict__ maskp,
    const float* __restrict__ a0p, const float* __restrict__ a1p,
    const float* __restrict__ a2p, const float* __restrict__ a3p,
    const float* __restrict__ q1p, const float* __restrict__ k1p,
    const float* __restrict__ q2p, const float* __restrict__ k2p,
    const float* __restrict__ wlp,
    float* __restrict__ outp)
{
    __shared__ __align__(16) ushort hb[Nc][136];
    __shared__ __align__(16) ushort hlo[Nc][136];
    __shared__ __align__(16) ushort Pb[Nc][72];
    __shared__ float aL[4][Dc];
    __shared__ float star_s[Dc];
    __shared__ float kk_s[Dc], qq_s[Dc];
    __shared__ float vv_s[Dc], ww_s[Dc];
    __shared__ float m_s[Nc];
    __shared__ float beta_s[Nc];
    __shared__ float star_part[4][Dc];
    __shared__ float Ssum[4];

    const int b      = blockIdx.x;
    const int tid    = threadIdx.x;
    const int lane   = tid & 63;
    const int wv     = tid >> 6;
    const int lane15 = lane & 15;
    const int quad   = lane >> 4;

    // ---- stage: hidden -> hb/hlo (bf16 split, RNE), a -> aL, mask -> m_s
    {
        const float4* hp4 = (const float4*)(hid + (size_t)b * (Nc * Dc));
        for (int idx = tid; idx < (Nc * Dc) / 4; idx += BDIM) {
            const int r = idx >> 5;
            const int c = (idx & 31) * 4;
            const float4 v = hp4[idx];
            ushort4 hi4, lo4;
            hi4.x = f2bf(v.x); lo4.x = f2bf(v.x - bf2f(hi4.x));
            hi4.y = f2bf(v.y); lo4.y = f2bf(v.y - bf2f(hi4.y));
            hi4.z = f2bf(v.z); lo4.z = f2bf(v.z - bf2f(hi4.z));
            hi4.w = f2bf(v.w); lo4.w = f2bf(v.w - bf2f(hi4.w));
            *(ushort4*)&hb[r][c]  = hi4;
            *(ushort4*)&hlo[r][c] = lo4;
        }
        if (tid < 128) {
            const int t = tid >> 5, c4 = tid & 31;
            const float* ap = (t == 0) ? a0p : (t == 1) ? a1p : (t == 2) ? a2p : a3p;
            *(float4*)&aL[t][c4 * 4] = *(const float4*)&ap[c4 * 4];
        }
        if (tid < Nc) m_s[tid] = maskp[b * Nc + tid];
    }
    __syncthreads();

    // ---- star init: masked average
    if (tid < Dc) {
        float s = 0.f, ms = 0.f;
        for (int i = 0; i < Nc; ++i) {
            const float hv = bf2f(hb[i][tid]) + bf2f(hlo[i][tid]);
            s = fmaf(hv, m_s[i], s);
            ms += m_s[i];
        }
        star_s[tid] = s / ms;
    }
    __syncthreads();

    float s2[8][4];   // sate slab (C-layout), survives into the gate

    for (int step = 0; step < 2; ++step) {
        // ---- matvec phase 1: kk = k1^T star, qq = q2^T star (no barrier
        // after: consumed by mv2 only after BAR_a; latency overlaps Phase A)
        if (tid < Dc) {
            const int c = tid;
            float s = 0.f;
            for (int d = 0; d < Dc; ++d) s = fmaf(star_s[d], k1p[d * Dc + c], s);
            kk_s[c] = s;
        } else {
            const int c = tid - Dc;
            float s = 0.f;
            for (int d = 0; d < Dc; ++d) s = fmaf(star_s[d], q2p[d * Dc + c], s);
            qq_s[c] = s;
        }

        // ---- Phase A: relation logits via split-bf16 MFMA.
        f32x4 eacc[4][4];   // [t][ntile]
#pragma unroll
        for (int t = 0; t < 4; ++t)
#pragma unroll
            for (int n = 0; n < 4; ++n) eacc[t][n] = (f32x4)0.f;

        const int arow = wv * 16 + lane15;
#pragma unroll
        for (int kc = 0; kc < 4; ++kc) {
            const int ko = kc * 32 + quad * 8;
            const bf16x8 hh = *(const bf16x8*)&hb[arow][ko];
            const bf16x8 hl = *(const bf16x8*)&hlo[arow][ko];
            float hx[8];
#pragma unroll
            for (int e = 0; e < 8; ++e)
                hx[e] = bf2f((ushort)hh[e]) + bf2f((ushort)hl[e]);
            bf16x8 Ahi[4], Alo[4];
#pragma unroll
            for (int t = 0; t < 4; ++t) {
                const float4 a0 = *(const float4*)&aL[t][ko];
                const float4 a1 = *(const float4*)&aL[t][ko + 4];
                const float p0 = hx[0] * a0.x, p1 = hx[1] * a0.y;
                const float p2 = hx[2] * a0.z, p3 = hx[3] * a0.w;
                const float p4 = hx[4] * a1.x, p5 = hx[5] * a1.y;
                const float p6 = hx[6] * a1.z, p7 = hx[7] * a1.w;
                // trunc-split: hi = trunc(p), lo = trunc(p - hi) -- the split
                // self-compensates, A = hi+lo matches p to ~2^-16.
                const unsigned int h0 = pkt(p0, p1), h1 = pkt(p2, p3);
                const unsigned int h2 = pkt(p4, p5), h3 = pkt(p6, p7);
                const float r0 = p0 - u2f_lo(h0), r1 = p1 - u2f_hi(h0);
                const float r2 = p2 - u2f_lo(h1), r3 = p3 - u2f_hi(h1);
                const float r4 = p4 - u2f_lo(h2), r5 = p5 - u2f_hi(h2);
                const float r6 = p6 - u2f_lo(h3), r7 = p7 - u2f_hi(h3);
                const unsigned int l0 = pkt(r0, r1), l1 = pkt(r2, r3);
                const unsigned int l2 = pkt(r4, r5), l3 = pkt(r6, r7);
                union { bf16x8 v; uint4 u; } A_, L_;
                A_.u = make_uint4(h0, h1, h2, h3);
                L_.u = make_uint4(l0, l1, l2, l3);
                Ahi[t] = A_.v;
                Alo[t] = L_.v;
            }
#pragma unroll
            for (int n = 0; n < 4; ++n) {
                const int brow = n * 16 + lane15;
                const bf16x8 Bh = *(const bf16x8*)&hb[brow][ko];
                const bf16x8 Bl = *(const bf16x8*)&hlo[brow][ko];
#pragma unroll
                for (int t = 0; t < 4; ++t) {
                    eacc[t][n] = MFMA16(Ahi[t], Bh, eacc[t][n]);
                    eacc[t][n] = MFMA16(Ahi[t], Bl, eacc[t][n]);
                    eacc[t][n] = MFMA16(Alo[t], Bh, eacc[t][n]);
                }
            }
        }

        // ---- selection by adj + leaky (static register indexing)
        float lg[4][4];   // [ntile][reg]
#pragma unroll
        for (int n = 0; n < 4; ++n) {
#pragma unroll
            for (int r = 0; r < 4; ++r) {
                const int i = wv * 16 + quad * 4 + r;
                const int j = n * 16 + lane15;
                const int t = adj[(size_t)b * 4096 + i * 64 + j];
                const float v0 = eacc[0][n][r], v1 = eacc[1][n][r];
                const float v2 = eacc[2][n][r], v3 = eacc[3][n][r];
                const float sel = (t == 1) ? v0 : (t == 2) ? v1 : (t == 3) ? v2 : v3;
                const float e = (t >= 1 && t <= 4) ? ((sel >= 0.f) ? sel : 0.2f * sel)
                                                   : NEG_BIG_F;
                lg[n][r] = e;
            }
        }

        // ---- in-register softmax over j -> P (bf16 LDS, RNE)
#pragma unroll
        for (int r = 0; r < 4; ++r) {
            float mx = fmaxf(fmaxf(lg[0][r], lg[1][r]), fmaxf(lg[2][r], lg[3][r]));
            mx = rmax16(mx);
            float pr[4], s = 0.f;
#pragma unroll
            for (int n = 0; n < 4; ++n) { pr[n] = __expf(lg[n][r] - mx); s += pr[n]; }
            s = rsum16(s);
            const float inv = 1.f / s;
            const int irow = wv * 16 + quad * 4 + r;
#pragma unroll
            for (int n = 0; n < 4; ++n)
                Pb[irow][n * 16 + lane15] = f2bf(pr[n] * inv);
        }
        __syncthreads();   // BAR_a: kk/qq ready for mv2 (Pb same-wave anyway)

        // ---- matvec phase 2: vv = q1 kk / sqrtD, ww = k2 qq / sqrtD
        // (no barrier after: consumed after BAR_b; overlaps Phase B)
        if (tid < Dc) {
            const int c = tid;
            float s = 0.f;
            for (int e4 = 0; e4 < Dc; e4 += 4) {
                const float4 qv = *(const float4*)&q1p[c * Dc + e4];
                s = fmaf(qv.w, kk_s[e4 + 3], fmaf(qv.z, kk_s[e4 + 2],
                    fmaf(qv.y, kk_s[e4 + 1], fmaf(qv.x, kk_s[e4], s))));
            }
            vv_s[c] = s * INV_SQRT_D;
        } else {
            const int c = tid - Dc;
            float s = 0.f;
            for (int e4 = 0; e4 < Dc; e4 += 4) {
                const float4 kv = *(const float4*)&k2p[c * Dc + e4];
                s = fmaf(kv.w, qq_s[e4 + 3], fmaf(kv.z, qq_s[e4 + 2],
                    fmaf(kv.y, qq_s[e4 + 1], fmaf(kv.x, qq_s[e4], s))));
            }
            ww_s[c] = s * INV_SQRT_D;
        }

        // ---- Phase B: sate1 = P @ sate
        f32x4 s1[8];
#pragma unroll
        for (int nd = 0; nd < 8; ++nd) s1[nd] = (f32x4)0.f;
#pragma unroll
        for (int kc2 = 0; kc2 < 2; ++kc2) {
            const int ko = kc2 * 32 + quad * 8;
            const bf16x8 Pa = *(const bf16x8*)&Pb[wv * 16 + lane15][ko];
#pragma unroll
            for (int nd = 0; nd < 8; ++nd) {
                const int dc = nd * 16 + lane15;
                bf16x8 Bf;
#pragma unroll
                for (int jj = 0; jj < 8; ++jj) Bf[jj] = (short)hb[ko + jj][dc];
                s1[nd] = MFMA16(Pa, Bf, s1[nd]);
            }
        }
        __syncthreads();   // BAR_b: vv/ww ready (cross-wave reads below)

        // ---- alpha blend: sate2 = (1-alpha)*sate1 + alpha*star
        float vvv[8], stv[8];
#pragma unroll
        for (int nt = 0; nt < 8; ++nt) {
            vvv[nt] = vv_s[nt * 16 + lane15];
            stv[nt] = star_s[nt * 16 + lane15];
        }
#pragma unroll
        for (int r = 0; r < 4; ++r) {
            float part = 0.f;
#pragma unroll
            for (int nt = 0; nt < 8; ++nt) part = fmaf(s1[nt][r], vvv[nt], part);
            const float al = rsum16(part);
#pragma unroll
            for (int nt = 0; nt < 8; ++nt)
                s2[nt][r] = (1.f - al) * s1[nt][r] + al * stv[nt];
        }

        // ---- beta logits (masked, finite sentinel)
        float www[8];
#pragma unroll
        for (int nt = 0; nt < 8; ++nt) www[nt] = ww_s[nt * 16 + lane15];
        float bm[4];
#pragma unroll
        for (int r = 0; r < 4; ++r) {
            float part = 0.f;
#pragma unroll
            for (int nt = 0; nt < 8; ++nt) part = fmaf(s2[nt][r], www[nt], part);
            const float bj = rsum16(part);
            const int j = wv * 16 + quad * 4 + r;
            bm[r] = (m_s[j] == 0.f) ? NEG_BIG_F : bj;
            if (lane15 == 0) beta_s[j] = bm[r];
        }
        __syncthreads();   // BAR_c: beta_s ready

        // ---- star = softmax(beta) @ sate2 : per-wave partials + sate2 -> LDS
        {
            float mx = NEG_BIG_F;
#pragma unroll
            for (int j4 = 0; j4 < 16; ++j4) {
                const float4 bv = *(const float4*)&beta_s[j4 * 4];
                mx = fmaxf(mx, fmaxf(fmaxf(bv.x, bv.y), fmaxf(bv.z, bv.w)));
            }
            float p[4];
#pragma unroll
            for (int r = 0; r < 4; ++r) p[r] = __expf(bm[r] - mx);
            float part[8];
#pragma unroll
            for (int nt = 0; nt < 8; ++nt) {
                float v = 0.f;
#pragma unroll
                for (int r = 0; r < 4; ++r) v = fmaf(p[r], s2[nt][r], v);
                v += __shfl_xor(v, 16, 64);
                v += __shfl_xor(v, 32, 64);
                part[nt] = v;
            }
            if (lane < 16) {
#pragma unroll
                for (int nt = 0; nt < 8; ++nt)
                    star_part[wv][nt * 16 + lane15] = part[nt];
            }
            // per-wave softmax denominator partial (saves 64-exp recompute)
            float pw = p[0] + p[1] + p[2] + p[3];
            pw += __shfl_xor(pw, 16, 64);
            pw += __shfl_xor(pw, 32, 64);
            if (lane == 0) Ssum[wv] = pw;

            // sate2 -> hb/hlo (RNE: hb-hi consumed standalone by Phase B/gate)
#pragma unroll
            for (int nt = 0; nt < 8; ++nt) {
#pragma unroll
                for (int r = 0; r < 4; ++r) {
                    const float v = s2[nt][r];
                    const ushort hi = f2bf(v);
                    const ushort lo = f2bf(v - bf2f(hi));
                    const int row = wv * 16 + quad * 4 + r;
                    const int c   = nt * 16 + lane15;
                    hb[row][c]  = hi;
                    hlo[row][c] = lo;
                }
            }
        }
        __syncthreads();   // BAR_d: star_part/Ssum ready
        if (tid < Dc) {
            const float S = Ssum[0] + Ssum[1] + Ssum[2] + Ssum[3];
            const float tot = star_part[0][tid] + star_part[1][tid]
                            + star_part[2][tid] + star_part[3][tid];
            star_s[tid] = tot / S;
        }
        __syncthreads();   // BAR_e: star_s ready for next step
    }

    // ---- gate GEMM: logits = [hidden, sate2] @ W^T via MFMA (trunc-packed
    // conversions: 1-op pkt instead of 5-op f2bf; logits feed sigmoid only)
    f32x4 g[8];
#pragma unroll
    for (int n = 0; n < 8; ++n) g[n] = (f32x4)0.f;
    const int arow_g = wv * 16 + lane15;
    const float* hrowA = hid + ((size_t)b * 64 + arow_g) * Dc;
#pragma unroll
    for (int kc = 0; kc < 8; ++kc) {
        bf16x8 Ah, Al;
        const bool has_lo = (kc >= 4);
        if (!has_lo) {
            const int co = kc * 32 + quad * 8;
            const float4 h0 = *(const float4*)&hrowA[co];
            const float4 h1 = *(const float4*)&hrowA[co + 4];
            union { bf16x8 v; uint4 u; } U;
            U.u = make_uint4(pkt(h0.x, h0.y), pkt(h0.z, h0.w),
                             pkt(h1.x, h1.y), pkt(h1.z, h1.w));
            Ah = U.v;
        } else {
            const int co = (kc - 4) * 32 + quad * 8;
            Ah = *(const bf16x8*)&hb[arow_g][co];
            Al = *(const bf16x8*)&hlo[arow_g][co];
        }
#pragma unroll
        for (int n = 0; n < 8; ++n) {
            const int orow = n * 16 + lane15;
            const float* wr = wlp + orow * 256 + kc * 32 + quad * 8;
            const float4 w0 = *(const float4*)&wr[0];
            const float4 w1 = *(const float4*)&wr[4];
            union { bf16x8 v; uint4 u; } Wu;
            Wu.u = make_uint4(pkt(w0.x, w0.y), pkt(w0.z, w0.w),
                              pkt(w1.x, w1.y), pkt(w1.z, w1.w));
            g[n] = MFMA16(Ah, Wu.v, g[n]);
            if (has_lo) g[n] = MFMA16(Al, Wu.v, g[n]);
        }
    }

    // ---- epilogue: out = g*hidden + (1-g)*sate2 ; star output
#pragma unroll
    for (int n = 0; n < 8; ++n) {
#pragma unroll
        for (int r = 0; r < 4; ++r) {
            const int i = wv * 16 + quad * 4 + r;
            const int o = n * 16 + lane15;
            const float gg = 1.f / (1.f + __expf(-g[n][r]));
            const float hv = hid[((size_t)b * 64 + i) * Dc + o];
            outp[((size_t)b * 64 + i) * Dc + o] = gg * hv + (1.f - gg) * s2[n][r];
        }
    }
    if (tid < Dc)
        outp[(size_t)Bc * Nc * Dc + (size_t)b * Dc + tid] = star_s[tid];
}

extern "C" void kernel_launch(void* const* d_in, const int* in_sizes, int n_in,
                              void* d_out, int out_size, void* d_ws, size_t ws_size,
                              hipStream_t stream) {
    const float* hid  = (const float*)d_in[0];
    const int*   adj  = (const int*)d_in[1];
    const float* mask = (const float*)d_in[2];
    const float* a0   = (const float*)d_in[3];
    const float* a1   = (const float*)d_in[4];
    const float* a2   = (const float*)d_in[5];
    const float* a3   = (const float*)d_in[6];
    const float* q1   = (const float*)d_in[7];
    const float* k1   = (const float*)d_in[8];
    const float* q2   = (const float*)d_in[9];
    const float* k2   = (const float*)d_in[10];
    const float* wl   = (const float*)d_in[11];
    float* out = (float*)d_out;

    star_agg_kernel<<<Bc, BDIM, 0, stream>>>(hid, adj, mask, a0, a1, a2, a3,
                                             q1, k1, q2, k2, wl, out);
}